// Round 8
// baseline (314.230 us; speedup 1.0000x reference)
//
#include <hip/hip_runtime.h>
#include <hip/hip_bf16.h>

namespace {

constexpr int kS  = 4096;   // sequence length
constexpr int kD  = 64;     // head dim
constexpr int kQB = 256;    // q-rows per block (8 waves x 32)
constexpr int kKV = 64;     // kv-rows per iteration
constexpr int kBH = 2 * 16; // B*H
constexpr int kNT = kS / kKV;
constexpr int kNWG = (kS / kQB) * kBH;  // 512 workgroups

typedef __attribute__((ext_vector_type(8))) short bf16x8;
typedef __attribute__((ext_vector_type(4))) short s16x4;
typedef __attribute__((ext_vector_type(4))) float f32x4;
typedef __attribute__((ext_vector_type(16))) float f32x16;
typedef __attribute__((ext_vector_type(2))) unsigned int u32x2;
typedef unsigned short u16;
typedef unsigned int u32;

constexpr float SCL = 0.18033688011112042f;  // (1/sqrt(64)) * log2(e)

__device__ __forceinline__ u16 f2bf(float f) {
  union { __hip_bfloat16 h; u16 u; } c;
  c.h = __float2bfloat16(f);
  return c.u;
}

// pack two f32->bf16 into one u32 (slot 2w = low16, 2w+1 = high16).
// Plain casts: compiler fuses to v_cvt_pk_bf16_f32 (m240: hand-asm is slower).
__device__ __forceinline__ u32 pkbf(float lo, float hi) {
  return (u32)f2bf(lo) | ((u32)f2bf(hi) << 16);
}

__device__ __forceinline__ u32x2 plswap2(u32 a, u32 b) {
  return __builtin_amdgcn_permlane32_swap(a, b, false, false);
}

// Direction-immune cross-half reduce: {r0,r1} = {[x_lo,x_lo],[x_hi,x_hi]}
// in SOME order under either swap convention; combining both is safe.
__device__ __forceinline__ float xhalf_max(float x) {
  union { float f; u32 u; } c; c.f = x;
  const u32x2 r = plswap2(c.u, c.u);
  union { u32 u; float f; } a, b; a.u = r[0]; b.u = r[1];
  return fmaxf(a.f, b.f);
}

__device__ __forceinline__ float xhalf_sum(float x) {
  union { float f; u32 u; } c; c.f = x;
  const u32x2 r = plswap2(c.u, c.u);
  union { u32 u; float f; } a, b; a.u = r[0]; b.u = r[1];
  return a.f + b.f;
}

// Convention-adaptive half swap: on return a = [a_lo, b_lo], b = [a_hi, b_hi]
// regardless of the hardware's swap direction (c1 = probe result).
__device__ __forceinline__ void halfswap(u32& a, u32& b, bool c1) {
  if (c1) {
    const u32x2 r = plswap2(a, b);
    a = r[0]; b = r[1];
  } else {
    const u32x2 r = plswap2(b, a);
    b = r[0]; a = r[1];
  }
}

__device__ __forceinline__ void gload_lds16(const void* g, void* l) {
  __builtin_amdgcn_global_load_lds(
      (const __attribute__((address_space(1))) unsigned int*)g,
      (__attribute__((address_space(3))) unsigned int*)l, 16, 0, 0);
}

// V^T LDS swizzle (verified round 2): element index for V^T[d][k].
__device__ __forceinline__ int vt_idx(int d, int k) {
  const int swz = (((d >> 4) & 3) << 4) ^ ((d & 15) << 2);
  return d * kKV + (k ^ swz);
}

// ---------------- pre-pass: f32 -> bf16 for Q(scaled),K,V in one launch ----
__global__ __launch_bounds__(256)
void cvt3_bf16(const float* __restrict__ Q, const float* __restrict__ K,
               const float* __restrict__ V, u16* __restrict__ dst, int n8) {
  const int i = blockIdx.x * 256 + threadIdx.x;
  if (i >= 3 * n8) return;
  const float* src;
  float scl;
  int j;
  if (i < n8)           { src = Q; scl = SCL;  j = i; }
  else if (i < 2 * n8)  { src = K; scl = 1.0f; j = i - n8; }
  else                  { src = V; scl = 1.0f; j = i - 2 * n8; }
  const float4 a = *(const float4*)(src + (size_t)j * 8);
  const float4 b = *(const float4*)(src + (size_t)j * 8 + 4);
  union { u16 us[8]; uint4 q; } p;
  p.us[0] = f2bf(a.x * scl); p.us[1] = f2bf(a.y * scl);
  p.us[2] = f2bf(a.z * scl); p.us[3] = f2bf(a.w * scl);
  p.us[4] = f2bf(b.x * scl); p.us[5] = f2bf(b.y * scl);
  p.us[6] = f2bf(b.z * scl); p.us[7] = f2bf(b.w * scl);
  *(uint4*)(dst + (size_t)i * 8) = p.q;
}

// ---------------- main kernel: 32x32 swapped QK^T, lane-local softmax ------
// QK^T: S^T[k][q] via mfma_f32_32x32x16(A=K rows, B=Q^T). Both operands use
//   slot rule k = 16*ks + 8*(lane>>5) + j -> true hw k-mapping cancels.
// C (verified m74/m101): col(q)=lane&31, row(k)=(reg&3)+8*(reg>>2)+4*(lane>>5).
// PV: A = V^T (same slot rule), B = P^T repacked so slot rule matches:
//   needed at (h,j): from half h'=(j>>2), reg 8m+4h+(j&3)  [m = ks&1]
//   -> P0..P3 = pk pairs, halfswap(P0,P2), halfswap(P1,P3).
__global__ __launch_bounds__(512, 4)
void attn_fwd_bf16(const u16* __restrict__ Qb, const u16* __restrict__ Kb,
                   const u16* __restrict__ Vb, float* __restrict__ Og) {
  __shared__ __align__(16) u16 Klds[2][kKV * kD];   // 2 x 8 KB row-major+swz
  __shared__ __align__(16) u16 Vt[2][kD * kKV];     // 2 x 8 KB V^T swizzled

  const int tid  = threadIdx.x;
  const int lane = tid & 63;
  const int w    = tid >> 6;
  const int l31  = lane & 31;
  const int h    = lane >> 5;

  // Detect permlane32_swap direction once (wave-uniform).
  bool conv1;
  {
    const u32x2 pr = plswap2((u32)lane, 0u);
    conv1 = __all(pr[0] == (u32)((lane < 32) ? lane : 0));
  }

  // XCD-chunked swizzle (T1): 512 blocks, 8 XCDs -> 64 contiguous per XCD.
  const int wg   = (blockIdx.x & 7) * (kNWG / 8) + (blockIdx.x >> 3);
  const int bh   = wg >> 4;        // head (16 q-blocks per head)
  const int qblk = wg & 15;

  const size_t base = (size_t)bh * kS * kD;
  const int qb = qblk * kQB + w * 32;   // this wave's 32 q-rows

  // ---- Q fragments: lane holds Q[qb+l31][16*ks + 8*h + j], pre-scaled ----
  bf16x8 qf[4];
  {
    const u16* qp = Qb + base + (size_t)(qb + l31) * kD + 8 * h;
#pragma unroll
    for (int ks = 0; ks < 4; ++ks) qf[ks] = *(const bf16x8*)(qp + 16 * ks);
  }

  f32x16 oacc0 = {0,0,0,0,0,0,0,0,0,0,0,0,0,0,0,0};
  f32x16 oacc1 = {0,0,0,0,0,0,0,0,0,0,0,0,0,0,0,0};
  float m_run = -__builtin_inff();
  float l_run = 0.0f;

  const u16* Kh = Kb + base;
  const u16* Vh = Vb + base;

  // V transpose ownership (waves 0-3): 4x4 block (k0..k0+3, d0..d0+3)
  const int k0 = (tid & 15) * 4;
  const int d0 = ((tid >> 4) & 15) * 4;

  ushort4 vr[4];

  // K staging (waves 4-7): 2 x gload_lds per thread, pre-swizzled source
  auto stageK = [&](const u16* Ktile, u16* Kbuf) {
    const int wv = w - 4;
#pragma unroll
    for (int p = 0; p < 2; ++p) {
      const int L = wv * 2048 + p * 1024 + lane * 16;  // byte offset in tile
      const int row = L >> 7;
      const int colb = (L & 127) ^ ((row & 7) << 4);
      gload_lds16(Ktile + row * kD + (colb >> 1), Kbuf + (wv * 1024 + p * 512));
    }
  };
  auto loadV = [&](const u16* Vtile) {
#pragma unroll
    for (int i = 0; i < 4; ++i)
      vr[i] = *(const ushort4*)(Vtile + (k0 + i) * kD + d0);
  };
  auto writeVt = [&](u16* Vbuf) {
#pragma unroll
    for (int j = 0; j < 4; ++j) {
      s16x4 col;
      col[0] = (short)vr[0][j]; col[1] = (short)vr[1][j];
      col[2] = (short)vr[2][j]; col[3] = (short)vr[3][j];
      *(s16x4*)&Vbuf[vt_idx(d0 + j, k0)] = col;
    }
  };

  // ---- prologue: stage tile 0 ----
  if (w >= 4) {
    stageK(Kh, Klds[0]);
  } else {
    loadV(Vh);
    writeVt(Vt[0]);
  }
  __syncthreads();

  int cur = 0;
  for (int t = 0; t < kNT; ++t) {
    const bool pf = (t + 1 < kNT);
    if (pf) {
      if (w >= 4) stageK(Kh + (size_t)(t + 1) * kKV * kD, Klds[cur ^ 1]);
      else        loadV(Vh + (size_t)(t + 1) * kKV * kD);
    }

    // ---- QK^T: two 32x32 S^T tiles (A = K rows, B = Q^T) ----
    f32x16 s0, s1;
    __builtin_amdgcn_s_setprio(1);
    {
      const int sw = (l31 & 7) << 4;
      {
        const char* kbp = (const char*)Klds[cur] + l31 * 128;
        f32x16 acc = {0,0,0,0,0,0,0,0,0,0,0,0,0,0,0,0};
#pragma unroll
        for (int ks = 0; ks < 4; ++ks) {
          const bf16x8 kf = *(const bf16x8*)(kbp + ((32 * ks + 16 * h) ^ sw));
          acc = __builtin_amdgcn_mfma_f32_32x32x16_bf16(kf, qf[ks], acc, 0, 0, 0);
        }
        s0 = acc;
      }
      {
        const char* kbp = (const char*)Klds[cur] + (32 + l31) * 128;
        f32x16 acc = {0,0,0,0,0,0,0,0,0,0,0,0,0,0,0,0};
#pragma unroll
        for (int ks = 0; ks < 4; ++ks) {
          const bf16x8 kf = *(const bf16x8*)(kbp + ((32 * ks + 16 * h) ^ sw));
          acc = __builtin_amdgcn_mfma_f32_32x32x16_bf16(kf, qf[ks], acc, 0, 0, 0);
        }
        s1 = acc;
      }
    }
    __builtin_amdgcn_s_setprio(0);

    // ---- lane-local online softmax with defer-max (T13) ----
    {
      float mx = s0[0];
#pragma unroll
      for (int r = 1; r < 16; ++r) mx = fmaxf(mx, s0[r]);
#pragma unroll
      for (int r = 0; r < 16; ++r) mx = fmaxf(mx, s1[r]);
      mx = xhalf_max(mx);
      if (!__all(mx - m_run <= 8.0f)) {
        const float mnew  = fmaxf(m_run, mx);
        const float alpha = exp2f(m_run - mnew);
        m_run = mnew;
        l_run *= alpha;
        oacc0 *= alpha;
        oacc1 *= alpha;
      }
      float ps = 0.0f;
#pragma unroll
      for (int r = 0; r < 16; ++r) {
        s0[r] = exp2f(s0[r] - m_run);
        ps += s0[r];
      }
#pragma unroll
      for (int r = 0; r < 16; ++r) {
        s1[r] = exp2f(s1[r] - m_run);
        ps += s1[r];
      }
      l_run += xhalf_sum(ps);
    }

    // ---- P repack: pk pairs + convention-adaptive half swaps ----
    bf16x8 pfr[4];
#pragma unroll
    for (int ks = 0; ks < 4; ++ks) {
      const int b8 = (ks & 1) * 8;
      u32 P0, P1, P2, P3;
      if (ks < 2) {
        P0 = pkbf(s0[b8 + 0], s0[b8 + 1]);
        P1 = pkbf(s0[b8 + 2], s0[b8 + 3]);
        P2 = pkbf(s0[b8 + 4], s0[b8 + 5]);
        P3 = pkbf(s0[b8 + 6], s0[b8 + 7]);
      } else {
        P0 = pkbf(s1[b8 + 0], s1[b8 + 1]);
        P1 = pkbf(s1[b8 + 2], s1[b8 + 3]);
        P2 = pkbf(s1[b8 + 4], s1[b8 + 5]);
        P3 = pkbf(s1[b8 + 6], s1[b8 + 7]);
      }
      halfswap(P0, P2, conv1);
      halfswap(P1, P3, conv1);
      union { u32 wd[4]; bf16x8 v; } u;
      u.wd[0] = P0; u.wd[1] = P1; u.wd[2] = P2; u.wd[3] = P3;
      pfr[ks] = u.v;
    }

    // ---- PV: O^T += V^T * P^T (A = V^T rows, B = P^T) ----
    __builtin_amdgcn_s_setprio(1);
#pragma unroll
    for (int dt = 0; dt < 2; ++dt) {
      const int d = dt * 32 + l31;
#pragma unroll
      for (int ks = 0; ks < 4; ++ks) {
        const int kk = 16 * ks + 8 * h;
        const s16x4 lo = *(const s16x4*)&Vt[cur][vt_idx(d, kk)];
        const s16x4 hi = *(const s16x4*)&Vt[cur][vt_idx(d, kk + 4)];
        const bf16x8 vf =
            __builtin_shufflevector(lo, hi, 0, 1, 2, 3, 4, 5, 6, 7);
        if (dt == 0)
          oacc0 = __builtin_amdgcn_mfma_f32_32x32x16_bf16(vf, pfr[ks], oacc0, 0, 0, 0);
        else
          oacc1 = __builtin_amdgcn_mfma_f32_32x32x16_bf16(vf, pfr[ks], oacc1, 0, 0, 0);
      }
    }
    __builtin_amdgcn_s_setprio(0);

    if (pf && w < 4) writeVt(Vt[cur ^ 1]);  // waits vmcnt on vr use
    __syncthreads();               // drains gload_lds; publishes Vt writes
    cur ^= 1;
  }

  // ---- epilogue: lane owns q-row l31; d = dt*32 + 8*rq + 4*h + m ----
  {
    const float inv = 1.0f / l_run;
    float* op = Og + base + (size_t)(qb + l31) * kD;
#pragma unroll
    for (int rq = 0; rq < 4; ++rq) {
      f32x4 o0 = {oacc0[4 * rq + 0], oacc0[4 * rq + 1],
                  oacc0[4 * rq + 2], oacc0[4 * rq + 3]};
      o0 *= inv;
      *(f32x4*)(op + 8 * rq + 4 * h) = o0;
      f32x4 o1 = {oacc1[4 * rq + 0], oacc1[4 * rq + 1],
                  oacc1[4 * rq + 2], oacc1[4 * rq + 3]};
      o1 *= inv;
      *(f32x4*)(op + 32 + 8 * rq + 4 * h) = o1;
    }
  }
}

// ---------------- fallback (f32 direct, used if ws too small) -------
__global__ __launch_bounds__(256)
void attn_fwd_f32(const float* __restrict__ Qg, const float* __restrict__ Kg,
                  const float* __restrict__ Vg, float* __restrict__ Og) {
  __shared__ __align__(16) u16 Klds[kKV * kD];
  __shared__ __align__(16) u16 Vts[kD * kKV];

  const int tid  = threadIdx.x;
  const int lane = tid & 63;
  const int w    = tid >> 6;
  const int g    = lane >> 4;
  const int lq   = lane & 15;

  const size_t base = (size_t)blockIdx.y * kS * kD;
  const int qb = blockIdx.x * 128 + w * 32;

  bf16x8 qf[2][2];
#pragma unroll
  for (int st = 0; st < 2; ++st) {
    const float* qp = Qg + base + (size_t)(qb + st * 16 + lq) * kD + 8 * g;
#pragma unroll
    for (int dh = 0; dh < 2; ++dh) {
      const float4 a = *(const float4*)(qp + dh * 32);
      const float4 b = *(const float4*)(qp + dh * 32 + 4);
      bf16x8 f;
      f[0] = (short)f2bf(a.x * SCL); f[1] = (short)f2bf(a.y * SCL);
      f[2] = (short)f2bf(a.z * SCL); f[3] = (short)f2bf(a.w * SCL);
      f[4] = (short)f2bf(b.x * SCL); f[5] = (short)f2bf(b.y * SCL);
      f[6] = (short)f2bf(b.z * SCL); f[7] = (short)f2bf(b.w * SCL);
      qf[st][dh] = f;
    }
  }

  f32x4 oacc[2][4];
#pragma unroll
  for (int st = 0; st < 2; ++st)
#pragma unroll
    for (int dt = 0; dt < 4; ++dt) oacc[st][dt] = f32x4{0.f, 0.f, 0.f, 0.f};
  float m_run[2] = {-__builtin_inff(), -__builtin_inff()};
  float l_run[2] = {0.0f, 0.0f};

  const int r  = tid >> 2;
  const int c0 = (tid & 3) * 16;

  for (int kv = 0; kv < kS; kv += kKV) {
    __syncthreads();
    {
      const float* kp = Kg + base + (size_t)(kv + r) * kD + c0;
      const float* vp = Vg + base + (size_t)(kv + r) * kD + c0;
      float4 kq[4], vq[4];
#pragma unroll
      for (int j = 0; j < 4; ++j) kq[j] = *(const float4*)(kp + 4 * j);
#pragma unroll
      for (int j = 0; j < 4; ++j) vq[j] = *(const float4*)(vp + 4 * j);
      const float* kfp = (const float*)kq;
      const float* vfp = (const float*)vq;
      union { u16 us[8]; uint4 q; } p0, p1;
#pragma unroll
      for (int j = 0; j < 8; ++j) {
        p0.us[j] = f2bf(kfp[j]);
        p1.us[j] = f2bf(kfp[8 + j]);
      }
      char* kb = (char*)Klds + r * 128;
      const int sw = (r & 7) << 4;
      *(uint4*)(kb + ((c0 * 2) ^ sw))      = p0.q;
      *(uint4*)(kb + ((c0 * 2 + 16) ^ sw)) = p1.q;
#pragma unroll
      for (int j = 0; j < 16; ++j) Vts[vt_idx(c0 + j, r)] = f2bf(vfp[j]);
    }
    __syncthreads();

    f32x4 s[2][4];
#pragma unroll
    for (int kt = 0; kt < 4; ++kt) {
      const int krow = kt * 16 + lq;
      const char* kb = (const char*)Klds + krow * 128;
      const int sw = (krow & 7) << 4;
      const bf16x8 kf0 = *(const bf16x8*)(kb + ((16 * g) ^ sw));
      const bf16x8 kf1 = *(const bf16x8*)(kb + ((16 * g + 64) ^ sw));
#pragma unroll
      for (int st = 0; st < 2; ++st) {
        f32x4 acc = __builtin_amdgcn_mfma_f32_16x16x32_bf16(
            kf0, qf[st][0], f32x4{0.f, 0.f, 0.f, 0.f}, 0, 0, 0);
        s[st][kt] = __builtin_amdgcn_mfma_f32_16x16x32_bf16(
            kf1, qf[st][1], acc, 0, 0, 0);
      }
    }

    bf16x8 pfr[2][2];
#pragma unroll
    for (int st = 0; st < 2; ++st) {
      float mx = s[st][0][0];
#pragma unroll
      for (int kt = 0; kt < 4; ++kt)
#pragma unroll
        for (int rr = 0; rr < 4; ++rr) mx = fmaxf(mx, s[st][kt][rr]);
      mx = fmaxf(mx, __shfl_xor(mx, 16));
      mx = fmaxf(mx, __shfl_xor(mx, 32));
      const float mnew  = fmaxf(m_run[st], mx);
      const float alpha = exp2f(m_run[st] - mnew);
      m_run[st] = mnew;
      float ps = 0.0f;
#pragma unroll
      for (int kt = 0; kt < 4; ++kt)
#pragma unroll
        for (int rr = 0; rr < 4; ++rr) {
          const float e = exp2f(s[st][kt][rr] - mnew);
          s[st][kt][rr] = e;
          ps += e;
        }
      ps += __shfl_xor(ps, 16);
      ps += __shfl_xor(ps, 32);
      l_run[st] = l_run[st] * alpha + ps;
#pragma unroll
      for (int dt = 0; dt < 4; ++dt) oacc[st][dt] *= alpha;
#pragma unroll
      for (int kc = 0; kc < 2; ++kc) {
        bf16x8 f;
#pragma unroll
        for (int i = 0; i < 4; ++i) {
          f[i]     = (short)f2bf(s[st][2 * kc][i]);
          f[4 + i] = (short)f2bf(s[st][2 * kc + 1][i]);
        }
        pfr[st][kc] = f;
      }
    }

#pragma unroll
    for (int dt = 0; dt < 4; ++dt) {
      const int d = dt * 16 + lq;
#pragma unroll
      for (int kc = 0; kc < 2; ++kc) {
        const s16x4 lo = *(const s16x4*)&Vts[vt_idx(d, kc * 32 + 4 * g)];
        const s16x4 hi = *(const s16x4*)&Vts[vt_idx(d, kc * 32 + 16 + 4 * g)];
        const bf16x8 vf =
            __builtin_shufflevector(lo, hi, 0, 1, 2, 3, 4, 5, 6, 7);
#pragma unroll
        for (int st = 0; st < 2; ++st)
          oacc[st][dt] = __builtin_amdgcn_mfma_f32_16x16x32_bf16(
              vf, pfr[st][kc], oacc[st][dt], 0, 0, 0);
      }
    }
  }

#pragma unroll
  for (int st = 0; st < 2; ++st) {
    const float inv = 1.0f / l_run[st];
    float* op = Og + base + (size_t)(qb + st * 16 + lq) * kD;
#pragma unroll
    for (int dt = 0; dt < 4; ++dt) {
      f32x4 o = oacc[st][dt];
      o *= inv;
      *(f32x4*)(op + dt * 16 + 4 * g) = o;
    }
  }
}

}  // namespace

extern "C" void kernel_launch(void* const* d_in, const int* in_sizes, int n_in,
                              void* d_out, int out_size, void* d_ws, size_t ws_size,
                              hipStream_t stream) {
  const float* Q = (const float*)d_in[0];
  const float* K = (const float*)d_in[1];
  const float* V = (const float*)d_in[2];
  float* O = (float*)d_out;
  const int n = in_sizes[0];                 // B*H*S*D elements per tensor
  const size_t tbytes = (size_t)n * 2;       // bf16 bytes per tensor

  if (ws_size >= 3 * tbytes) {
    u16* Qb = (u16*)d_ws;
    u16* Kb = Qb + n;
    u16* Vb = Kb + n;
    const int n8 = n / 8;
    const int cblk = (3 * n8 + 255) / 256;
    cvt3_bf16<<<cblk, 256, 0, stream>>>(Q, K, V, Qb, n8);
    attn_fwd_bf16<<<dim3(kNWG), 512, 0, stream>>>(Qb, Kb, Vb, O);
  } else {
    dim3 grid(kS / 128, kBH);
    attn_fwd_f32<<<grid, 256, 0, stream>>>(Q, K, V, O);
  }
}

// Round 9
// 273.985 us; speedup vs baseline: 1.1469x; 1.1469x over previous
//
#include <hip/hip_runtime.h>
#include <hip/hip_bf16.h>

namespace {

constexpr int kS  = 4096;   // sequence length
constexpr int kD  = 64;     // head dim
constexpr int kQB = 256;    // q-rows per block (8 waves x 32)
constexpr int kTile = 128;  // kv-rows staged per barrier
constexpr int kSub  = 64;   // kv-rows per compute sub-iteration
constexpr int kBH = 2 * 16; // B*H
constexpr int kNT = kS / kTile;          // 32 staged tiles
constexpr int kNWG = (kS / kQB) * kBH;   // 512 workgroups

typedef __attribute__((ext_vector_type(8))) short bf16x8;
typedef __attribute__((ext_vector_type(4))) short s16x4;
typedef __attribute__((ext_vector_type(4))) float f32x4;
typedef unsigned short u16;

constexpr float SCL = 0.18033688011112042f;  // (1/sqrt(64)) * log2(e)

__device__ __forceinline__ u16 f2bf(float f) {
  union { __hip_bfloat16 h; u16 u; } c;
  c.h = __float2bfloat16(f);
  return c.u;
}

__device__ __forceinline__ void gload_lds16(const void* g, void* l) {
  __builtin_amdgcn_global_load_lds(
      (const __attribute__((address_space(1))) unsigned int*)g,
      (__attribute__((address_space(3))) unsigned int*)l, 16, 0, 0);
}

// V^T LDS swizzle (verified r2/r6): element index for V^T[d][k], k in 0..127.
__device__ __forceinline__ int vt_idx(int d, int k) {
  const int swz = (((d >> 4) & 3) << 4) ^ ((d & 15) << 2);
  return d * kTile + (k ^ swz);
}

// ---------------- pre-pass: f32 -> bf16 for K,V in one launch ----
__global__ __launch_bounds__(256)
void cvt2_bf16(const float* __restrict__ K, const float* __restrict__ V,
               u16* __restrict__ dst, int n8) {
  const int i = blockIdx.x * 256 + threadIdx.x;
  if (i >= 2 * n8) return;
  const float* src;
  int j;
  if (i < n8) { src = K; j = i; }
  else        { src = V; j = i - n8; }
  const float4 a = *(const float4*)(src + (size_t)j * 8);
  const float4 b = *(const float4*)(src + (size_t)j * 8 + 4);
  union { u16 us[8]; uint4 q; } p;
  p.us[0] = f2bf(a.x); p.us[1] = f2bf(a.y);
  p.us[2] = f2bf(a.z); p.us[3] = f2bf(a.w);
  p.us[4] = f2bf(b.x); p.us[5] = f2bf(b.y);
  p.us[6] = f2bf(b.z); p.us[7] = f2bf(b.w);
  *(uint4*)(dst + (size_t)i * 8) = p.q;
}

// ---------------- main kernel ----------------
// r6-verified math; staging batched: 128 kv-rows per barrier, 2x64 compute.
// Waves 4-7 stage K via global_load_lds; waves 0-3 stage V via 4x4 reg
// transpose (two passes k0 and k0+64). Q loaded f32 directly (no reuse).
__global__ __launch_bounds__(512)
void attn_fwd_bf16(const float* __restrict__ Qg, const u16* __restrict__ Kb,
                   const u16* __restrict__ Vb, float* __restrict__ Og) {
  __shared__ __align__(16) u16 Klds[2][kTile * kD];   // 2 x 16 KB rows+swz
  __shared__ __align__(16) u16 Vt[2][kD * kTile];     // 2 x 16 KB V^T swz

  const int tid  = threadIdx.x;
  const int lane = tid & 63;
  const int w    = tid >> 6;
  const int g    = lane >> 4;
  const int lq   = lane & 15;

  // XCD-chunked swizzle (T1): 512 blocks, 8 XCDs -> 64 contiguous per XCD.
  const int wg   = (blockIdx.x & 7) * (kNWG / 8) + (blockIdx.x >> 3);
  const int bh   = wg >> 4;        // head (16 q-blocks per head)
  const int qblk = wg & 15;

  const size_t base = (size_t)bh * kS * kD;
  const int qb = qblk * kQB + w * 32;   // this wave's 32 q-rows

  // ---- Q fragments: f32 load + inline scaled cvt (once per kernel) ----
  bf16x8 qf[2][2];
#pragma unroll
  for (int st = 0; st < 2; ++st) {
    const float* qp = Qg + base + (size_t)(qb + st * 16 + lq) * kD + 8 * g;
#pragma unroll
    for (int dh = 0; dh < 2; ++dh) {
      const float4 a = *(const float4*)(qp + dh * 32);
      const float4 b = *(const float4*)(qp + dh * 32 + 4);
      bf16x8 f;
      f[0] = (short)f2bf(a.x * SCL); f[1] = (short)f2bf(a.y * SCL);
      f[2] = (short)f2bf(a.z * SCL); f[3] = (short)f2bf(a.w * SCL);
      f[4] = (short)f2bf(b.x * SCL); f[5] = (short)f2bf(b.y * SCL);
      f[6] = (short)f2bf(b.z * SCL); f[7] = (short)f2bf(b.w * SCL);
      qf[st][dh] = f;
    }
  }

  f32x4 oacc[2][4];
#pragma unroll
  for (int st = 0; st < 2; ++st)
#pragma unroll
    for (int dt = 0; dt < 4; ++dt) oacc[st][dt] = f32x4{0.f, 0.f, 0.f, 0.f};
  float m_run[2] = {-__builtin_inff(), -__builtin_inff()};
  float l_run[2] = {0.0f, 0.0f};

  const u16* Kh = Kb + base;
  const u16* Vh = Vb + base;

  // V transpose ownership (waves 0-3): 4x4 blocks at (k0 + 64p, d0)
  const int k0 = (tid & 15) * 4;
  const int d0 = ((tid >> 4) & 15) * 4;

  ushort4 vr[2][4];

  // K staging (waves 4-7): 4 x gload_lds per thread, pre-swizzled source
  auto stageK = [&](const u16* Ktile, u16* Kbuf) {
    const int wv = w - 4;
#pragma unroll
    for (int p = 0; p < 4; ++p) {
      const int L = wv * 4096 + p * 1024 + lane * 16;  // byte offset in tile
      const int row = L >> 7;                          // 0..127
      const int colb = (L & 127) ^ ((row & 7) << 4);
      gload_lds16(Ktile + row * kD + (colb >> 1), Kbuf + (wv * 2048 + p * 512));
    }
  };
  auto loadV = [&](const u16* Vtile) {
#pragma unroll
    for (int p = 0; p < 2; ++p)
#pragma unroll
      for (int i = 0; i < 4; ++i)
        vr[p][i] = *(const ushort4*)(Vtile + (k0 + 64 * p + i) * kD + d0);
  };
  auto writeVt = [&](u16* Vbuf) {
#pragma unroll
    for (int p = 0; p < 2; ++p)
#pragma unroll
      for (int j = 0; j < 4; ++j) {
        s16x4 col;
        col[0] = (short)vr[p][0][j]; col[1] = (short)vr[p][1][j];
        col[2] = (short)vr[p][2][j]; col[3] = (short)vr[p][3][j];
        *(s16x4*)&Vbuf[vt_idx(d0 + j, k0 + 64 * p)] = col;
      }
  };

  // ---- prologue: stage tile 0 ----
  if (w >= 4) {
    stageK(Kh, Klds[0]);
  } else {
    loadV(Vh);
    writeVt(Vt[0]);
  }
  __syncthreads();

  int cur = 0;
  for (int t = 0; t < kNT; ++t) {
    const bool pf = (t + 1 < kNT);
    if (pf) {
      if (w >= 4) stageK(Kh + (size_t)(t + 1) * kTile * kD, Klds[cur ^ 1]);
      else        loadV(Vh + (size_t)(t + 1) * kTile * kD);
    }

#pragma unroll
    for (int sub = 0; sub < 2; ++sub) {
      // ---- QK^T: S^T tiles (A = K rows, B = Q^T) ----
      f32x4 s[2][4];
      __builtin_amdgcn_s_setprio(1);
#pragma unroll
      for (int kt = 0; kt < 4; ++kt) {
        const int krow = sub * kSub + kt * 16 + lq;
        const char* kbp = (const char*)Klds[cur] + krow * 128;
        const int sw = (krow & 7) << 4;
        const bf16x8 kf0 = *(const bf16x8*)(kbp + ((16 * g) ^ sw));
        const bf16x8 kf1 = *(const bf16x8*)(kbp + ((16 * g + 64) ^ sw));
#pragma unroll
        for (int st = 0; st < 2; ++st) {
          f32x4 acc = __builtin_amdgcn_mfma_f32_16x16x32_bf16(
              kf0, qf[st][0], f32x4{0.f, 0.f, 0.f, 0.f}, 0, 0, 0);
          s[st][kt] = __builtin_amdgcn_mfma_f32_16x16x32_bf16(
              kf1, qf[st][1], acc, 0, 0, 0);
        }
      }
      __builtin_amdgcn_s_setprio(0);

      // ---- online softmax with defer-max (T13) ----
      bf16x8 pfr[2][2];
#pragma unroll
      for (int st = 0; st < 2; ++st) {
        float mx = s[st][0][0];
#pragma unroll
        for (int kt = 0; kt < 4; ++kt)
#pragma unroll
          for (int rr = 0; rr < 4; ++rr) mx = fmaxf(mx, s[st][kt][rr]);
        mx = fmaxf(mx, __shfl_xor(mx, 16));
        mx = fmaxf(mx, __shfl_xor(mx, 32));
        if (!__all(mx - m_run[st] <= 8.0f)) {
          const float mnew  = fmaxf(m_run[st], mx);
          const float alpha = exp2f(m_run[st] - mnew);
          m_run[st] = mnew;
          l_run[st] *= alpha;
#pragma unroll
          for (int dt = 0; dt < 4; ++dt) oacc[st][dt] *= alpha;
        }
        float ps = 0.0f;
#pragma unroll
        for (int kt = 0; kt < 4; ++kt)
#pragma unroll
          for (int rr = 0; rr < 4; ++rr) {
            const float e = exp2f(s[st][kt][rr] - m_run[st]);
            s[st][kt][rr] = e;
            ps += e;
          }
        ps += __shfl_xor(ps, 16);
        ps += __shfl_xor(ps, 32);
        l_run[st] += ps;
        // P slot i of chunk kc maps k = kc*32 + 16*(i>>2) + 4*g + (i&3)
#pragma unroll
        for (int kc = 0; kc < 2; ++kc) {
          bf16x8 f;
#pragma unroll
          for (int i = 0; i < 4; ++i) {
            f[i]     = (short)f2bf(s[st][2 * kc][i]);
            f[4 + i] = (short)f2bf(s[st][2 * kc + 1][i]);
          }
          pfr[st][kc] = f;
        }
      }

      // ---- PV: O^T += V^T * P^T (b64 reads from swizzled V^T) ----
      __builtin_amdgcn_s_setprio(1);
#pragma unroll
      for (int dt = 0; dt < 4; ++dt) {
        const int d = dt * 16 + lq;
#pragma unroll
        for (int kc = 0; kc < 2; ++kc) {
          const int kkk = sub * kSub + kc * 32;
          const s16x4 lo = *(const s16x4*)&Vt[cur][vt_idx(d, kkk + 4 * g)];
          const s16x4 hi = *(const s16x4*)&Vt[cur][vt_idx(d, kkk + 16 + 4 * g)];
          const bf16x8 vf =
              __builtin_shufflevector(lo, hi, 0, 1, 2, 3, 4, 5, 6, 7);
#pragma unroll
          for (int st = 0; st < 2; ++st)
            oacc[st][dt] = __builtin_amdgcn_mfma_f32_16x16x32_bf16(
                vf, pfr[st][kc], oacc[st][dt], 0, 0, 0);
        }
      }
      __builtin_amdgcn_s_setprio(0);
    }

    if (pf && w < 4) writeVt(Vt[cur ^ 1]);  // waits vmcnt on vr use
    __syncthreads();               // drains gload_lds; publishes Vt writes
    cur ^= 1;
  }

  // ---- epilogue: lane holds O rows; normalize and store ----
#pragma unroll
  for (int st = 0; st < 2; ++st) {
    const float inv = 1.0f / l_run[st];
    float* op = Og + base + (size_t)(qb + st * 16 + lq) * kD;
#pragma unroll
    for (int dt = 0; dt < 4; ++dt) {
      f32x4 o = oacc[st][dt];
      o *= inv;
      *(f32x4*)(op + dt * 16 + 4 * g) = o;
    }
  }
}

// ---------------- fallback (f32 direct, used if ws too small) -------
__device__ __forceinline__ int vt_idx64(int d, int k) {
  const int swz = (((d >> 4) & 3) << 4) ^ ((d & 15) << 2);
  return d * 64 + (k ^ swz);
}

__global__ __launch_bounds__(256)
void attn_fwd_f32(const float* __restrict__ Qg, const float* __restrict__ Kg,
                  const float* __restrict__ Vg, float* __restrict__ Og) {
  __shared__ __align__(16) u16 Klds[64 * kD];
  __shared__ __align__(16) u16 Vts[kD * 64];

  const int tid  = threadIdx.x;
  const int lane = tid & 63;
  const int w    = tid >> 6;
  const int g    = lane >> 4;
  const int lq   = lane & 15;

  const size_t base = (size_t)blockIdx.y * kS * kD;
  const int qb = blockIdx.x * 128 + w * 32;

  bf16x8 qf[2][2];
#pragma unroll
  for (int st = 0; st < 2; ++st) {
    const float* qp = Qg + base + (size_t)(qb + st * 16 + lq) * kD + 8 * g;
#pragma unroll
    for (int dh = 0; dh < 2; ++dh) {
      const float4 a = *(const float4*)(qp + dh * 32);
      const float4 b = *(const float4*)(qp + dh * 32 + 4);
      bf16x8 f;
      f[0] = (short)f2bf(a.x * SCL); f[1] = (short)f2bf(a.y * SCL);
      f[2] = (short)f2bf(a.z * SCL); f[3] = (short)f2bf(a.w * SCL);
      f[4] = (short)f2bf(b.x * SCL); f[5] = (short)f2bf(b.y * SCL);
      f[6] = (short)f2bf(b.z * SCL); f[7] = (short)f2bf(b.w * SCL);
      qf[st][dh] = f;
    }
  }

  f32x4 oacc[2][4];
#pragma unroll
  for (int st = 0; st < 2; ++st)
#pragma unroll
    for (int dt = 0; dt < 4; ++dt) oacc[st][dt] = f32x4{0.f, 0.f, 0.f, 0.f};
  float m_run[2] = {-__builtin_inff(), -__builtin_inff()};
  float l_run[2] = {0.0f, 0.0f};

  const int r  = tid >> 2;
  const int c0 = (tid & 3) * 16;

  for (int kv = 0; kv < kS; kv += 64) {
    __syncthreads();
    {
      const float* kp = Kg + base + (size_t)(kv + r) * kD + c0;
      const float* vp = Vg + base + (size_t)(kv + r) * kD + c0;
      float4 kq[4], vq[4];
#pragma unroll
      for (int j = 0; j < 4; ++j) kq[j] = *(const float4*)(kp + 4 * j);
#pragma unroll
      for (int j = 0; j < 4; ++j) vq[j] = *(const float4*)(vp + 4 * j);
      const float* kfp = (const float*)kq;
      const float* vfp = (const float*)vq;
      union { u16 us[8]; uint4 q; } p0, p1;
#pragma unroll
      for (int j = 0; j < 8; ++j) {
        p0.us[j] = f2bf(kfp[j]);
        p1.us[j] = f2bf(kfp[8 + j]);
      }
      char* kb = (char*)Klds + r * 128;
      const int sw = (r & 7) << 4;
      *(uint4*)(kb + ((c0 * 2) ^ sw))      = p0.q;
      *(uint4*)(kb + ((c0 * 2 + 16) ^ sw)) = p1.q;
#pragma unroll
      for (int j = 0; j < 16; ++j) Vts[vt_idx64(c0 + j, r)] = f2bf(vfp[j]);
    }
    __syncthreads();

    f32x4 s[2][4];
#pragma unroll
    for (int kt = 0; kt < 4; ++kt) {
      const int krow = kt * 16 + lq;
      const char* kb = (const char*)Klds + krow * 128;
      const int sw = (krow & 7) << 4;
      const bf16x8 kf0 = *(const bf16x8*)(kb + ((16 * g) ^ sw));
      const bf16x8 kf1 = *(const bf16x8*)(kb + ((16 * g + 64) ^ sw));
#pragma unroll
      for (int st = 0; st < 2; ++st) {
        f32x4 acc = __builtin_amdgcn_mfma_f32_16x16x32_bf16(
            kf0, qf[st][0], f32x4{0.f, 0.f, 0.f, 0.f}, 0, 0, 0);
        s[st][kt] = __builtin_amdgcn_mfma_f32_16x16x32_bf16(
            kf1, qf[st][1], acc, 0, 0, 0);
      }
    }

    bf16x8 pfr[2][2];
#pragma unroll
    for (int st = 0; st < 2; ++st) {
      float mx = s[st][0][0];
#pragma unroll
      for (int kt = 0; kt < 4; ++kt)
#pragma unroll
        for (int rr = 0; rr < 4; ++rr) mx = fmaxf(mx, s[st][kt][rr]);
      mx = fmaxf(mx, __shfl_xor(mx, 16));
      mx = fmaxf(mx, __shfl_xor(mx, 32));
      const float mnew  = fmaxf(m_run[st], mx);
      const float alpha = exp2f(m_run[st] - mnew);
      m_run[st] = mnew;
      float ps = 0.0f;
#pragma unroll
      for (int kt = 0; kt < 4; ++kt)
#pragma unroll
        for (int rr = 0; rr < 4; ++rr) {
          const float e = exp2f(s[st][kt][rr] - mnew);
          s[st][kt][rr] = e;
          ps += e;
        }
      ps += __shfl_xor(ps, 16);
      ps += __shfl_xor(ps, 32);
      l_run[st] = l_run[st] * alpha + ps;
#pragma unroll
      for (int dt = 0; dt < 4; ++dt) oacc[st][dt] *= alpha;
#pragma unroll
      for (int kc = 0; kc < 2; ++kc) {
        bf16x8 f;
#pragma unroll
        for (int i = 0; i < 4; ++i) {
          f[i]     = (short)f2bf(s[st][2 * kc][i]);
          f[4 + i] = (short)f2bf(s[st][2 * kc + 1][i]);
        }
        pfr[st][kc] = f;
      }
    }

#pragma unroll
    for (int dt = 0; dt < 4; ++dt) {
      const int d = dt * 16 + lq;
#pragma unroll
      for (int kc = 0; kc < 2; ++kc) {
        const s16x4 lo = *(const s16x4*)&Vts[vt_idx64(d, kc * 32 + 4 * g)];
        const s16x4 hi = *(const s16x4*)&Vts[vt_idx64(d, kc * 32 + 16 + 4 * g)];
        const bf16x8 vf =
            __builtin_shufflevector(lo, hi, 0, 1, 2, 3, 4, 5, 6, 7);
#pragma unroll
        for (int st = 0; st < 2; ++st)
          oacc[st][dt] = __builtin_amdgcn_mfma_f32_16x16x32_bf16(
              vf, pfr[st][kc], oacc[st][dt], 0, 0, 0);
      }
    }
  }

#pragma unroll
  for (int st = 0; st < 2; ++st) {
    const float inv = 1.0f / l_run[st];
    float* op = Og + base + (size_t)(qb + st * 16 + lq) * kD;
#pragma unroll
    for (int dt = 0; dt < 4; ++dt) {
      f32x4 o = oacc[st][dt];
      o *= inv;
      *(f32x4*)(op + dt * 16 + 4 * g) = o;
    }
  }
}

}  // namespace

extern "C" void kernel_launch(void* const* d_in, const int* in_sizes, int n_in,
                              void* d_out, int out_size, void* d_ws, size_t ws_size,
                              hipStream_t stream) {
  const float* Q = (const float*)d_in[0];
  const float* K = (const float*)d_in[1];
  const float* V = (const float*)d_in[2];
  float* O = (float*)d_out;
  const int n = in_sizes[0];                 // B*H*S*D elements per tensor
  const size_t tbytes = (size_t)n * 2;       // bf16 bytes per tensor

  if (ws_size >= 2 * tbytes) {
    u16* Kb = (u16*)d_ws;
    u16* Vb = Kb + n;
    const int n8 = n / 8;
    const int cblk = (2 * n8 + 255) / 256;
    cvt2_bf16<<<cblk, 256, 0, stream>>>(K, V, Kb, n8);
    attn_fwd_bf16<<<dim3(kNWG), 512, 0, stream>>>(Q, Kb, Vb, O);
  } else {
    dim3 grid(kS / 128, kBH);
    attn_fwd_f32<<<grid, 256, 0, stream>>>(Q, K, V, O);
  }
}